// Round 1
// baseline (180.735 us; speedup 1.0000x reference)
//
#include <hip/hip_runtime.h>

// Problem constants from the reference
#define BB 64
#define VV 8
#define JJ 17
#define HH 256
#define NN (BB * VV * JJ)   // 8704 gathered elements total

// Single-block kernel: 1024 threads (16 waves) on one CU.
// Each thread processes ~9 of the 8704 elements, computes -log(gathered val),
// then block-reduces and thread 0 writes mean to out[0].
__global__ __launch_bounds__(1024) void HeatmapCELoss_kernel(
    const float* __restrict__ kp,   // (B, V, J, 2) float32
    const float* __restrict__ hm,   // (B, V, 1, H, H) float32
    float* __restrict__ out)        // scalar float32
{
    const int tid = threadIdx.x;
    float sum = 0.0f;

    // Grid-stride (well, block-stride) loop over all 8704 elements.
    for (int i = tid; i < NN; i += 1024) {
        // keypoints are (x, y) pairs, contiguous -> vector load
        float2 k = ((const float2*)kp)[i];
        int x = (int)ceilf(k.x);
        int y = (int)ceilf(k.y);
        x = min(max(x, 0), HH - 1);
        y = min(max(y, 0), HH - 1);
        int bv = i / JJ;  // which (b, v) plane; compiler emits magic-mul for /17
        float val = hm[((size_t)bv * HH + (size_t)y) * HH + (size_t)x];
        sum += -__logf(val);
    }

    // Wave (64-lane) shuffle reduction
    #pragma unroll
    for (int off = 32; off > 0; off >>= 1)
        sum += __shfl_down(sum, off, 64);

    __shared__ float ws[16];
    const int wave = tid >> 6;
    if ((tid & 63) == 0) ws[wave] = sum;
    __syncthreads();

    if (wave == 0) {
        float s = (tid < 16) ? ws[tid] : 0.0f;
        #pragma unroll
        for (int off = 8; off > 0; off >>= 1)
            s += __shfl_down(s, off, 64);
        if (tid == 0) out[0] = s * (1.0f / (float)NN);
    }
}

extern "C" void kernel_launch(void* const* d_in, const int* in_sizes, int n_in,
                              void* d_out, int out_size, void* d_ws, size_t ws_size,
                              hipStream_t stream) {
    const float* kp = (const float*)d_in[0];  // keypoints_gt (64,8,17,2) f32
    const float* hm = (const float*)d_in[1];  // heatmap (64,8,1,256,256) f32
    float* out = (float*)d_out;

    HeatmapCELoss_kernel<<<1, 1024, 0, stream>>>(kp, hm, out);
}

// Round 2
// 162.190 us; speedup vs baseline: 1.1143x; 1.1143x over previous
//
#include <hip/hip_runtime.h>

// Problem constants from the reference
#define BB 64
#define VV 8
#define JJ 17
#define HH 256
#define NN (BB * VV * JJ)     // 8704 gathered elements total
#define NBLK (NN / 64)        // 136 blocks of one wave each (exact)

// Kernel A: one element per thread, 136 blocks x 64 threads across many CUs.
// All 8704 scattered gathers issue in parallel (one HBM-latency round),
// wave shuffle-reduce -> one partial per block into d_ws.
__global__ __launch_bounds__(64) void HeatmapCELoss_gather(
    const float* __restrict__ kp,   // (B, V, J, 2) float32
    const float* __restrict__ hm,   // (B, V, 1, H, H) float32
    float* __restrict__ ws)         // 136 partials
{
    const int i = blockIdx.x * 64 + threadIdx.x;   // i in [0, 8704)

    // keypoints are (x, y) pairs, contiguous -> coalesced float2 load
    float2 k = ((const float2*)kp)[i];
    int x = (int)ceilf(k.x);
    int y = (int)ceilf(k.y);
    x = min(max(x, 0), HH - 1);
    y = min(max(y, 0), HH - 1);
    int bv = i / JJ;   // (b,v) plane index; compiler emits magic-mul for /17

    float val = hm[((size_t)bv * HH + (size_t)y) * HH + (size_t)x];
    float s = -__logf(val);

    // 64-lane wave shuffle reduction
    #pragma unroll
    for (int off = 32; off > 0; off >>= 1)
        s += __shfl_down(s, off, 64);

    if (threadIdx.x == 0) ws[blockIdx.x] = s;
}

// Kernel B: single wave reduces the 136 partials and writes the mean.
__global__ __launch_bounds__(64) void HeatmapCELoss_reduce(
    const float* __restrict__ ws,
    float* __restrict__ out)
{
    const int t = threadIdx.x;
    float s = ws[t] + ws[t + 64];          // covers 0..127
    if (t < NBLK - 128) s += ws[t + 128];  // covers 128..135

    #pragma unroll
    for (int off = 32; off > 0; off >>= 1)
        s += __shfl_down(s, off, 64);

    if (t == 0) out[0] = s * (1.0f / (float)NN);
}

extern "C" void kernel_launch(void* const* d_in, const int* in_sizes, int n_in,
                              void* d_out, int out_size, void* d_ws, size_t ws_size,
                              hipStream_t stream) {
    const float* kp = (const float*)d_in[0];  // keypoints_gt (64,8,17,2) f32
    const float* hm = (const float*)d_in[1];  // heatmap (64,8,1,256,256) f32
    float* ws  = (float*)d_ws;                // 136 floats of scratch
    float* out = (float*)d_out;

    HeatmapCELoss_gather<<<NBLK, 64, 0, stream>>>(kp, hm, ws);
    HeatmapCELoss_reduce<<<1, 64, 0, stream>>>(ws, out);
}